// Round 6
// baseline (179.860 us; speedup 1.0000x reference)
//
#include <hip/hip_runtime.h>
#include <hip/hip_bf16.h>
#include <hip/hip_fp16.h>
#include <math.h>

typedef _Float16 half8 __attribute__((ext_vector_type(8)));
typedef float f32x4 __attribute__((ext_vector_type(4)));

__device__ __forceinline__ float tanh_fast(float v) {
  // tanh(v) = 1 - 2/(exp(2v)+1); saturates correctly (exp->inf => 1, ->0 => -1)
  float e = __expf(v + v);
  return 1.0f - 2.0f * __builtin_amdgcn_rcpf(e + 1.0f);
}

// ---------------------------------------------------------------------------
// Stage 1 (MFMA): h = tanh(x @ W^T + b_lin), row-normalized, stored fp16.
// W fp32->f16 into a 32KB XOR-swizzled LDS tile (byte ^= (row&7)<<4):
// ds_read_b128 conflict-free. 4 waves/block, 16 rows x 128 cols per wave via
// mfma_f32_16x16x32_f16. C mapping: col=l&15, row=(l>>4)*4+reg [m89/m91].
// ---------------------------------------------------------------------------
__global__ __launch_bounds__(256) void k_gemm_mfma(
    const float* __restrict__ x, const float* __restrict__ W,
    const float* __restrict__ bl, __half* __restrict__ hn, int N) {
  __shared__ _Float16 wsh[128 * 128];  // 32 KB, swizzled
  const int tid = threadIdx.x;
  const int wv = tid >> 6, lane = tid & 63;
  const int nb = blockIdx.x * 64;

  for (int i = tid; i < 2048; i += 256) {
    int row = i >> 4, cc = i & 15;
    const float4* wr = (const float4*)(W + row * 128 + cc * 8);
    float4 a = wr[0], b = wr[1];
    half8 h;
    h[0] = (_Float16)a.x; h[1] = (_Float16)a.y;
    h[2] = (_Float16)a.z; h[3] = (_Float16)a.w;
    h[4] = (_Float16)b.x; h[5] = (_Float16)b.y;
    h[6] = (_Float16)b.z; h[7] = (_Float16)b.w;
    *(half8*)((char*)wsh + row * 256 + ((cc * 16) ^ ((row & 7) << 4))) = h;
  }
  __syncthreads();

  const int row0 = nb + wv * 16;
  if (row0 >= N) return;  // after barrier; N%16==0 -> wave-granular guard

  const int r = lane & 15;  // A-row / B-col / C-col within tile
  const int g = lane >> 4;  // k-group (operands), row-group (C)

  half8 afrag[4];
  {
    const float4* xr = (const float4*)(x + (size_t)(row0 + r) * 128);
#pragma unroll
    for (int ks = 0; ks < 4; ++ks) {
      float4 lo = xr[ks * 8 + g * 2];
      float4 hi = xr[ks * 8 + g * 2 + 1];
      half8 a;
      a[0] = (_Float16)lo.x; a[1] = (_Float16)lo.y;
      a[2] = (_Float16)lo.z; a[3] = (_Float16)lo.w;
      a[4] = (_Float16)hi.x; a[5] = (_Float16)hi.y;
      a[6] = (_Float16)hi.z; a[7] = (_Float16)hi.w;
      afrag[ks] = a;
    }
  }

  f32x4 acc[8];
#pragma unroll
  for (int c = 0; c < 8; ++c) acc[c] = (f32x4){0.f, 0.f, 0.f, 0.f};
#pragma unroll
  for (int c = 0; c < 8; ++c) {
    const char* base = (const char*)wsh + (c * 16 + r) * 256;
    const int sw = ((c * 16 + r) & 7) << 4;
#pragma unroll
    for (int ks = 0; ks < 4; ++ks) {
      half8 b = *(const half8*)(base + ((ks * 64 + g * 16) ^ sw));
      acc[c] = __builtin_amdgcn_mfma_f32_16x16x32_f16(afrag[ks], b, acc[c],
                                                      0, 0, 0);
    }
  }

  float t[8][4];
  float ss[4] = {0.f, 0.f, 0.f, 0.f};
#pragma unroll
  for (int c = 0; c < 8; ++c) {
    float bv = bl[c * 16 + r];
#pragma unroll
    for (int j = 0; j < 4; ++j) {
      float tv = tanh_fast(acc[c][j] + bv);
      t[c][j] = tv;
      ss[j] = fmaf(tv, tv, ss[j]);
    }
  }
#pragma unroll
  for (int j = 0; j < 4; ++j) {
#pragma unroll
    for (int off = 8; off; off >>= 1) ss[j] += __shfl_xor(ss[j], off);
    ss[j] = 1.0f / fmaxf(sqrtf(ss[j]), 1e-8f);
  }
#pragma unroll
  for (int c = 0; c < 8; ++c)
#pragma unroll
    for (int j = 0; j < 4; ++j)
      hn[(size_t)(row0 + g * 4 + j) * 128 + c * 16 + r] =
          __float2half_rn(t[c][j] * ss[j]);
}

// ---------------------------------------------------------------------------
// CSR construction (col-sorted). N < 65536 so row/col pack into one u32.
// ---------------------------------------------------------------------------
__global__ void k_init_count(const int* __restrict__ cols,
                             const float* __restrict__ mask,
                             int* __restrict__ cnt, float* __restrict__ h0,
                             float* __restrict__ f_a, int N, int E) {
  int i = blockIdx.x * 256 + threadIdx.x;
  if (i < E) atomicAdd(cnt + cols[i], 1);
  if (i < N) {
    float v = fmaxf(mask[i], 0.0f);
    h0[i] = v;
    f_a[i] = v;
  }
}

__global__ __launch_bounds__(256) void k_scan_a(const int* __restrict__ cnt,
                                                int* __restrict__ bsum,
                                                int N) {
  __shared__ int s[256];
  int i = blockIdx.x * 256 + threadIdx.x;
  s[threadIdx.x] = (i < N) ? cnt[i] : 0;
  __syncthreads();
  for (int d = 128; d; d >>= 1) {
    if (threadIdx.x < d) s[threadIdx.x] += s[threadIdx.x + d];
    __syncthreads();
  }
  if (threadIdx.x == 0) bsum[blockIdx.x] = s[0];
}

// exclusive scan of <=256 block sums (single block)
__global__ __launch_bounds__(256) void k_scan_b(const int* __restrict__ bsum,
                                                int* __restrict__ bpre,
                                                int NB) {
  __shared__ int s[2][256];
  int t = threadIdx.x;
  int v = (t < NB) ? bsum[t] : 0;
  s[0][t] = v;
  __syncthreads();
  int a = 0;
  for (int d = 1; d < 256; d <<= 1) {
    int x = s[a][t];
    if (t >= d) x += s[a][t - d];
    s[a ^ 1][t] = x;
    __syncthreads();
    a ^= 1;
  }
  bpre[t] = s[a][t] - v;  // exclusive
}

__global__ __launch_bounds__(256) void k_scan_c(
    const int* __restrict__ cnt, const int* __restrict__ bpre,
    int* __restrict__ off, int* __restrict__ cursor, float* __restrict__ deg,
    int N, int E) {
  __shared__ int s[2][256];
  int t = threadIdx.x;
  int i = blockIdx.x * 256 + t;
  int v = (i < N) ? cnt[i] : 0;
  s[0][t] = v;
  __syncthreads();
  int a = 0;
  for (int d = 1; d < 256; d <<= 1) {
    int x = s[a][t];
    if (t >= d) x += s[a][t - d];
    s[a ^ 1][t] = x;
    __syncthreads();
    a ^= 1;
  }
  int excl = s[a][t] - v + bpre[blockIdx.x];
  if (i < N) {
    off[i] = excl;
    cursor[i] = excl;
    deg[i] = 1.0f;  // self-loop weight; edge weights atomically added later
  }
  if (i == 0) off[N] = E;
}

__global__ void k_build(const int* __restrict__ rows,
                        const int* __restrict__ cols, int* __restrict__ cursor,
                        uint2* __restrict__ rec, int E) {
  int e = blockIdx.x * 256 + threadIdx.x;
  if (e >= E) return;
  unsigned r = (unsigned)rows[e], c = (unsigned)cols[e];
  int pos = atomicAdd(cursor + c, 1);
  rec[pos] = make_uint2(r | (c << 16), (unsigned)e);
}

// ---------------------------------------------------------------------------
// Stage 2: edge cosine in col-sorted order. hn[col] is L1-hot (consecutive
// pos share col); hn[row] random. Writes ew[e] (output, scattered), raw
// weight sequentially to csr_w[pos], src16[pos], and accumulates deg[col].
// 8 lanes per edge.
// ---------------------------------------------------------------------------
__device__ __forceinline__ float dot8h(float4 a, float4 b) {
  const __half2* pa = (const __half2*)&a;
  const __half2* pb = (const __half2*)&b;
  float s = 0.0f;
#pragma unroll
  for (int i = 0; i < 4; ++i) {
    float2 fa = __half22float2(pa[i]);
    float2 fb = __half22float2(pb[i]);
    s = fmaf(fa.x, fb.x, s);
    s = fmaf(fa.y, fb.y, s);
  }
  return s;
}

__global__ __launch_bounds__(256) void k_edge_cos(
    const __half* __restrict__ hn, const uint2* __restrict__ rec,
    float* __restrict__ ew, float* __restrict__ csr_w,
    unsigned short* __restrict__ src16, float* __restrict__ deg, int E) {
  int t = blockIdx.x * 256 + threadIdx.x;
  int pos = t >> 3, sub = t & 7;
  if (pos >= E) return;
  uint2 rc = rec[pos];
  unsigned row = rc.x & 0xffffu, col = rc.x >> 16;
  const float4* hr = (const float4*)(hn + (size_t)row * 128);
  const float4* hc = (const float4*)(hn + (size_t)col * 128);
  float4 a0 = hr[sub], a1 = hr[sub + 8];
  float4 b0 = hc[sub], b1 = hc[sub + 8];
  float dot = dot8h(a0, b0) + dot8h(a1, b1);
#pragma unroll
  for (int off = 4; off; off >>= 1) dot += __shfl_xor(dot, off);
  if (sub == 0) {
    float w = fmaxf(dot, 0.0f);
    ew[rc.y] = w;
    csr_w[pos] = w;
    src16[pos] = (unsigned short)row;
    atomicAdd(deg + col, w);
  }
}

__global__ void k_rsd(const float* __restrict__ deg, float* __restrict__ rsd,
                      int N) {
  int n = blockIdx.x * 256 + threadIdx.x;
  if (n < N) rsd[n] = rsqrtf(deg[n]);
}

// ---------------------------------------------------------------------------
// One APPNP iteration, fused gather-reduce + update. 4 lanes per node (avg
// degree ~12 -> ~3 loop iters/lane; dependent src->f chain 4x shorter than
// thread-per-node). mode bit0: first iter, normalize csr_w in place
// (wn = raw * rsd[src] * rsd[n]) -- replaces the old k_wcsr pass.
// mode bit1: last iter, write fill = tanh(f - softplus(bias)) to d_out.
// ---------------------------------------------------------------------------
__global__ __launch_bounds__(256) void k_prop(
    const float* __restrict__ f_in, float* __restrict__ f_out,
    float* __restrict__ csr_w, const unsigned short* __restrict__ src16,
    const int* __restrict__ off, const float* __restrict__ h0,
    const float* __restrict__ rsd, const float* __restrict__ alpha_p,
    const float* __restrict__ bias_p, float* __restrict__ fill, int N,
    int mode) {
  int t = blockIdx.x * 256 + threadIdx.x;
  int n = t >> 2, sub = t & 3;
  if (n >= N) return;
  float rs_n = rsd[n];
  int s0 = off[n], s1 = off[n + 1];
  float part = 0.0f;
  if (mode & 1) {
    for (int i = s0 + sub; i < s1; i += 4) {
      int s = src16[i];
      float wn = csr_w[i] * rs_n * rsd[s];
      csr_w[i] = wn;  // segment owned by this node's 4 lanes; i unique
      part = fmaf(wn, f_in[s], part);
    }
  } else {
    for (int i = s0 + sub; i < s1; i += 4)
      part = fmaf(csr_w[i], f_in[src16[i]], part);
  }
  part += __shfl_xor(part, 1);
  part += __shfl_xor(part, 2);
  if (sub == 0) {
    float a = alpha_p[0];
    float agg = part + f_in[n] * rs_n * rs_n;  // self-loop: norm = 1/deg
    float fn = (1.0f - a) * agg + a * h0[n];
    if (mode & 2) {
      float b = bias_p[0];
      float sp = (b > 20.0f) ? b : log1pf(expf(b));
      fill[n] = tanhf(fn - sp);
    } else {
      f_out[n] = fn;
    }
  }
}

// ---------------------------------------------------------------------------
extern "C" void kernel_launch(void* const* d_in, const int* in_sizes, int n_in,
                              void* d_out, int out_size, void* d_ws,
                              size_t ws_size, hipStream_t stream) {
  const float* x = (const float*)d_in[0];
  const float* mask = (const float*)d_in[1];
  const int* ei = (const int*)d_in[2];  // [2, E] int32 (jax x64 disabled)
  const float* W = (const float*)d_in[3];
  const float* bl = (const float*)d_in[4];
  const float* alpha = (const float*)d_in[5];
  const float* bias = (const float*)d_in[6];

  const int D = 128;
  const int N = in_sizes[0] / D;  // 50000  (< 65536: u16 node ids)
  const int E = in_sizes[2] / 2;  // 600000
  const int* rows = ei;
  const int* cols = ei + E;

  float* fill = (float*)d_out;    // [N]
  float* ew = (float*)d_out + N;  // [E] edge_weights output slice

  // workspace carve-up (256B aligned)
  char* w = (char*)d_ws;
  size_t off_b = 0;
  auto alloc = [&](size_t bytes) -> void* {
    void* p = (void*)(w + off_b);
    off_b = (off_b + bytes + 255) & ~(size_t)255;
    return p;
  };
  __half* hn = (__half*)alloc((size_t)N * D * sizeof(__half));  // 12.8 MB
  int* cnt = (int*)alloc((size_t)N * sizeof(int));
  int* off = (int*)alloc((size_t)(N + 1) * sizeof(int));
  int* cursor = (int*)alloc((size_t)N * sizeof(int));
  int* bsum = (int*)alloc(256 * sizeof(int));
  int* bpre = (int*)alloc(256 * sizeof(int));
  uint2* rec = (uint2*)alloc((size_t)E * sizeof(uint2));    // 4.8 MB
  float* csr_w = (float*)alloc((size_t)E * sizeof(float));  // 2.4 MB
  unsigned short* src16 =
      (unsigned short*)alloc((size_t)E * sizeof(unsigned short));
  float* deg = (float*)alloc((size_t)N * sizeof(float));
  float* h0 = (float*)alloc((size_t)N * sizeof(float));
  float* f_a = (float*)alloc((size_t)N * sizeof(float));
  float* f_b = (float*)alloc((size_t)N * sizeof(float));
  float* rsd = (float*)alloc((size_t)N * sizeof(float));
  (void)ws_size;

  const int NB_N = (N + 255) / 256;  // 196 <= 256 (scan_b capacity)
  const int nb_E = (E + 255) / 256;

  hipMemsetAsync(cnt, 0, (size_t)N * sizeof(int), stream);
  // histogram cols + node inits (h0, f_a)
  k_init_count<<<nb_E, 256, 0, stream>>>(cols, mask, cnt, h0, f_a, N, E);
  // MFMA GEMM + tanh + normalize + fp16 store
  k_gemm_mfma<<<(N + 63) / 64, 256, 0, stream>>>(x, W, bl, hn, N);
  // exclusive scan of cnt -> off, cursor (+ deg=1 init)
  k_scan_a<<<NB_N, 256, 0, stream>>>(cnt, bsum, N);
  k_scan_b<<<1, 256, 0, stream>>>(bsum, bpre, NB_N);
  k_scan_c<<<NB_N, 256, 0, stream>>>(cnt, bpre, off, cursor, deg, N, E);
  // col-sorted edge records
  k_build<<<nb_E, 256, 0, stream>>>(rows, cols, cursor, rec, E);
  // cosine in sorted order -> ew + csr_w + src16 + deg accumulation
  k_edge_cos<<<(E * 8 + 255) / 256, 256, 0, stream>>>(hn, rec, ew, csr_w,
                                                      src16, deg, E);
  // rsqrt of degrees
  k_rsd<<<NB_N, 256, 0, stream>>>(deg, rsd, N);
  // K=5 APPNP iterations (gather-reduce; iter 0 normalizes csr_w in place)
  const float* fi = f_a;
  float* fo = f_b;
  for (int it = 0; it < 5; ++it) {
    int mode = (it == 0 ? 1 : 0) | (it == 4 ? 2 : 0);
    k_prop<<<(N * 4 + 255) / 256, 256, 0, stream>>>(
        fi, fo, csr_w, src16, off, h0, rsd, alpha, bias, fill, N, mode);
    const float* tmp = fo;
    fo = (float*)fi;
    fi = tmp;
  }
}

// Round 7
// 153.122 us; speedup vs baseline: 1.1746x; 1.1746x over previous
//
#include <hip/hip_runtime.h>
#include <hip/hip_bf16.h>
#include <hip/hip_fp16.h>
#include <math.h>

typedef _Float16 half8 __attribute__((ext_vector_type(8)));
typedef float f32x4 __attribute__((ext_vector_type(4)));

__device__ __forceinline__ float tanh_fast(float v) {
  // tanh(v) = 1 - 2/(exp(2v)+1); saturates correctly (exp->inf => 1, ->0 => -1)
  float e = __expf(v + v);
  return 1.0f - 2.0f * __builtin_amdgcn_rcpf(e + 1.0f);
}

// ---------------------------------------------------------------------------
// Stage 1 (MFMA): h = tanh(x @ W^T + b_lin), row-normalized, stored fp16.
// W fp32->f16 into a 32KB XOR-swizzled LDS tile (byte ^= (row&7)<<4):
// ds_read_b128 conflict-free. 4 waves/block, 16 rows x 128 cols per wave via
// mfma_f32_16x16x32_f16. C mapping: col=l&15, row=(l>>4)*4+reg [m89/m91].
// ---------------------------------------------------------------------------
__global__ __launch_bounds__(256) void k_gemm_mfma(
    const float* __restrict__ x, const float* __restrict__ W,
    const float* __restrict__ bl, __half* __restrict__ hn, int N) {
  __shared__ _Float16 wsh[128 * 128];  // 32 KB, swizzled
  const int tid = threadIdx.x;
  const int wv = tid >> 6, lane = tid & 63;
  const int nb = blockIdx.x * 64;

  for (int i = tid; i < 2048; i += 256) {
    int row = i >> 4, cc = i & 15;
    const float4* wr = (const float4*)(W + row * 128 + cc * 8);
    float4 a = wr[0], b = wr[1];
    half8 h;
    h[0] = (_Float16)a.x; h[1] = (_Float16)a.y;
    h[2] = (_Float16)a.z; h[3] = (_Float16)a.w;
    h[4] = (_Float16)b.x; h[5] = (_Float16)b.y;
    h[6] = (_Float16)b.z; h[7] = (_Float16)b.w;
    *(half8*)((char*)wsh + row * 256 + ((cc * 16) ^ ((row & 7) << 4))) = h;
  }
  __syncthreads();

  const int row0 = nb + wv * 16;
  if (row0 >= N) return;  // after barrier; N%16==0 -> wave-granular guard

  const int r = lane & 15;  // A-row / B-col / C-col within tile
  const int g = lane >> 4;  // k-group (operands), row-group (C)

  half8 afrag[4];
  {
    const float4* xr = (const float4*)(x + (size_t)(row0 + r) * 128);
#pragma unroll
    for (int ks = 0; ks < 4; ++ks) {
      float4 lo = xr[ks * 8 + g * 2];
      float4 hi = xr[ks * 8 + g * 2 + 1];
      half8 a;
      a[0] = (_Float16)lo.x; a[1] = (_Float16)lo.y;
      a[2] = (_Float16)lo.z; a[3] = (_Float16)lo.w;
      a[4] = (_Float16)hi.x; a[5] = (_Float16)hi.y;
      a[6] = (_Float16)hi.z; a[7] = (_Float16)hi.w;
      afrag[ks] = a;
    }
  }

  f32x4 acc[8];
#pragma unroll
  for (int c = 0; c < 8; ++c) acc[c] = (f32x4){0.f, 0.f, 0.f, 0.f};
#pragma unroll
  for (int c = 0; c < 8; ++c) {
    const char* base = (const char*)wsh + (c * 16 + r) * 256;
    const int sw = ((c * 16 + r) & 7) << 4;
#pragma unroll
    for (int ks = 0; ks < 4; ++ks) {
      half8 b = *(const half8*)(base + ((ks * 64 + g * 16) ^ sw));
      acc[c] = __builtin_amdgcn_mfma_f32_16x16x32_f16(afrag[ks], b, acc[c],
                                                      0, 0, 0);
    }
  }

  float t[8][4];
  float ss[4] = {0.f, 0.f, 0.f, 0.f};
#pragma unroll
  for (int c = 0; c < 8; ++c) {
    float bv = bl[c * 16 + r];
#pragma unroll
    for (int j = 0; j < 4; ++j) {
      float tv = tanh_fast(acc[c][j] + bv);
      t[c][j] = tv;
      ss[j] = fmaf(tv, tv, ss[j]);
    }
  }
#pragma unroll
  for (int j = 0; j < 4; ++j) {
#pragma unroll
    for (int off = 8; off; off >>= 1) ss[j] += __shfl_xor(ss[j], off);
    ss[j] = 1.0f / fmaxf(sqrtf(ss[j]), 1e-8f);
  }
#pragma unroll
  for (int c = 0; c < 8; ++c)
#pragma unroll
    for (int j = 0; j < 4; ++j)
      hn[(size_t)(row0 + g * 4 + j) * 128 + c * 16 + r] =
          __float2half_rn(t[c][j] * ss[j]);
}

// ---------------------------------------------------------------------------
// CSR construction (col-sorted). N < 65536 so row/col pack into one u32.
// ---------------------------------------------------------------------------
__global__ void k_init_count(const int* __restrict__ cols,
                             const float* __restrict__ mask,
                             int* __restrict__ cnt, float* __restrict__ h0,
                             float* __restrict__ f_a, int N, int E) {
  int i = blockIdx.x * 256 + threadIdx.x;
  if (i < E) atomicAdd(cnt + cols[i], 1);
  if (i < N) {
    float v = fmaxf(mask[i], 0.0f);
    h0[i] = v;
    f_a[i] = v;
  }
}

__global__ __launch_bounds__(256) void k_scan_a(const int* __restrict__ cnt,
                                                int* __restrict__ bsum,
                                                int N) {
  __shared__ int s[256];
  int i = blockIdx.x * 256 + threadIdx.x;
  s[threadIdx.x] = (i < N) ? cnt[i] : 0;
  __syncthreads();
  for (int d = 128; d; d >>= 1) {
    if (threadIdx.x < d) s[threadIdx.x] += s[threadIdx.x + d];
    __syncthreads();
  }
  if (threadIdx.x == 0) bsum[blockIdx.x] = s[0];
}

// exclusive scan of <=256 block sums (single block)
__global__ __launch_bounds__(256) void k_scan_b(const int* __restrict__ bsum,
                                                int* __restrict__ bpre,
                                                int NB) {
  __shared__ int s[2][256];
  int t = threadIdx.x;
  int v = (t < NB) ? bsum[t] : 0;
  s[0][t] = v;
  __syncthreads();
  int a = 0;
  for (int d = 1; d < 256; d <<= 1) {
    int x = s[a][t];
    if (t >= d) x += s[a][t - d];
    s[a ^ 1][t] = x;
    __syncthreads();
    a ^= 1;
  }
  bpre[t] = s[a][t] - v;  // exclusive
}

__global__ __launch_bounds__(256) void k_scan_c(
    const int* __restrict__ cnt, const int* __restrict__ bpre,
    int* __restrict__ off, int* __restrict__ cursor, int N, int E) {
  __shared__ int s[2][256];
  int t = threadIdx.x;
  int i = blockIdx.x * 256 + t;
  int v = (i < N) ? cnt[i] : 0;
  s[0][t] = v;
  __syncthreads();
  int a = 0;
  for (int d = 1; d < 256; d <<= 1) {
    int x = s[a][t];
    if (t >= d) x += s[a][t - d];
    s[a ^ 1][t] = x;
    __syncthreads();
    a ^= 1;
  }
  int excl = s[a][t] - v + bpre[blockIdx.x];
  if (i < N) {
    off[i] = excl;
    cursor[i] = excl;
  }
  if (i == 0) off[N] = E;
}

// rec[pos] = row | col<<16 (u32); perm[e] = pos (for the ew un-permute).
__global__ void k_build(const int* __restrict__ rows,
                        const int* __restrict__ cols, int* __restrict__ cursor,
                        unsigned* __restrict__ rec, int* __restrict__ perm,
                        int E) {
  int e = blockIdx.x * 256 + threadIdx.x;
  if (e >= E) return;
  unsigned r = (unsigned)rows[e], c = (unsigned)cols[e];
  int pos = atomicAdd(cursor + c, 1);
  rec[pos] = r | (c << 16);
  perm[e] = pos;
}

// ---------------------------------------------------------------------------
// Stage 2: edge cosine in col-sorted order. hn[col] is L1-hot (consecutive
// pos share col); hn[row] random (L3). 4 lanes/edge: 8 loads in flight per
// lane, 16 edges/wave (2x MLP vs 8-lane version). Sequential writes only.
// ---------------------------------------------------------------------------
__device__ __forceinline__ float dot8h(float4 a, float4 b) {
  const __half2* pa = (const __half2*)&a;
  const __half2* pb = (const __half2*)&b;
  float s = 0.0f;
#pragma unroll
  for (int i = 0; i < 4; ++i) {
    float2 fa = __half22float2(pa[i]);
    float2 fb = __half22float2(pb[i]);
    s = fmaf(fa.x, fb.x, s);
    s = fmaf(fa.y, fb.y, s);
  }
  return s;
}

__global__ __launch_bounds__(256) void k_edge_cos(
    const __half* __restrict__ hn, const unsigned* __restrict__ rec,
    float* __restrict__ csr_w, unsigned short* __restrict__ src16, int E) {
  int t = blockIdx.x * 256 + threadIdx.x;
  int pos = t >> 2, sub = t & 3;
  if (pos >= E) return;
  unsigned rc = rec[pos];
  unsigned row = rc & 0xffffu, col = rc >> 16;
  const float4* hr = (const float4*)(hn + (size_t)row * 128);  // 16 float4
  const float4* hc = (const float4*)(hn + (size_t)col * 128);
  float4 a0 = hr[sub], a1 = hr[sub + 4], a2 = hr[sub + 8], a3 = hr[sub + 12];
  float4 b0 = hc[sub], b1 = hc[sub + 4], b2 = hc[sub + 8], b3 = hc[sub + 12];
  float dot = dot8h(a0, b0) + dot8h(a1, b1) + dot8h(a2, b2) + dot8h(a3, b3);
  dot += __shfl_xor(dot, 1);
  dot += __shfl_xor(dot, 2);
  if (sub == 0) {
    csr_w[pos] = fmaxf(dot, 0.0f);
    src16[pos] = (unsigned short)row;
  }
}

// ---------------------------------------------------------------------------
// Fused: (a) un-permute raw weights to ew[e] (sequential write, random read
// of L2-resident csr_w); (b) deterministic segmented degree sum -> rsd
// (4 lanes/node). Runs after k_edge_cos, before k_prop iter 0.
// ---------------------------------------------------------------------------
__global__ __launch_bounds__(256) void k_unperm_rsd(
    const float* __restrict__ csr_w, const int* __restrict__ perm,
    const int* __restrict__ off, float* __restrict__ ew,
    float* __restrict__ rsd, int N, int E) {
  int t = blockIdx.x * 256 + threadIdx.x;
  if (t < E) ew[t] = csr_w[perm[t]];
  int n = t >> 2, sub = t & 3;
  if (n < N) {
    int s0 = off[n], s1 = off[n + 1];
    float s = 0.0f;
    for (int i = s0 + sub; i < s1; i += 4) s += csr_w[i];
    s += __shfl_xor(s, 1);
    s += __shfl_xor(s, 2);
    if (sub == 0) rsd[n] = rsqrtf(1.0f + s);  // self-loop weight 1
  }
}

// ---------------------------------------------------------------------------
// One APPNP iteration, fused gather-reduce + update. 4 lanes per node.
// mode bit0: first iter, normalize csr_w in place (wn = raw*rsd[src]*rsd[n]).
// mode bit1: last iter, write fill = tanh(f - softplus(bias)) to d_out.
// ---------------------------------------------------------------------------
__global__ __launch_bounds__(256) void k_prop(
    const float* __restrict__ f_in, float* __restrict__ f_out,
    float* __restrict__ csr_w, const unsigned short* __restrict__ src16,
    const int* __restrict__ off, const float* __restrict__ h0,
    const float* __restrict__ rsd, const float* __restrict__ alpha_p,
    const float* __restrict__ bias_p, float* __restrict__ fill, int N,
    int mode) {
  int t = blockIdx.x * 256 + threadIdx.x;
  int n = t >> 2, sub = t & 3;
  if (n >= N) return;
  float rs_n = rsd[n];
  int s0 = off[n], s1 = off[n + 1];
  float part = 0.0f;
  if (mode & 1) {
    for (int i = s0 + sub; i < s1; i += 4) {
      int s = src16[i];
      float wn = csr_w[i] * rs_n * rsd[s];
      csr_w[i] = wn;  // segment owned by this node's 4 lanes; i unique
      part = fmaf(wn, f_in[s], part);
    }
  } else {
    for (int i = s0 + sub; i < s1; i += 4)
      part = fmaf(csr_w[i], f_in[src16[i]], part);
  }
  part += __shfl_xor(part, 1);
  part += __shfl_xor(part, 2);
  if (sub == 0) {
    float a = alpha_p[0];
    float agg = part + f_in[n] * rs_n * rs_n;  // self-loop: norm = 1/deg
    float fn = (1.0f - a) * agg + a * h0[n];
    if (mode & 2) {
      float b = bias_p[0];
      float sp = (b > 20.0f) ? b : log1pf(expf(b));
      fill[n] = tanhf(fn - sp);
    } else {
      f_out[n] = fn;
    }
  }
}

// ---------------------------------------------------------------------------
extern "C" void kernel_launch(void* const* d_in, const int* in_sizes, int n_in,
                              void* d_out, int out_size, void* d_ws,
                              size_t ws_size, hipStream_t stream) {
  const float* x = (const float*)d_in[0];
  const float* mask = (const float*)d_in[1];
  const int* ei = (const int*)d_in[2];  // [2, E] int32 (jax x64 disabled)
  const float* W = (const float*)d_in[3];
  const float* bl = (const float*)d_in[4];
  const float* alpha = (const float*)d_in[5];
  const float* bias = (const float*)d_in[6];

  const int D = 128;
  const int N = in_sizes[0] / D;  // 50000  (< 65536: u16 node ids)
  const int E = in_sizes[2] / 2;  // 600000
  const int* rows = ei;
  const int* cols = ei + E;

  float* fill = (float*)d_out;    // [N]
  float* ew = (float*)d_out + N;  // [E] edge_weights output slice

  // workspace carve-up (256B aligned)
  char* w = (char*)d_ws;
  size_t off_b = 0;
  auto alloc = [&](size_t bytes) -> void* {
    void* p = (void*)(w + off_b);
    off_b = (off_b + bytes + 255) & ~(size_t)255;
    return p;
  };
  __half* hn = (__half*)alloc((size_t)N * D * sizeof(__half));  // 12.8 MB
  int* cnt = (int*)alloc((size_t)N * sizeof(int));
  int* off = (int*)alloc((size_t)(N + 1) * sizeof(int));
  int* cursor = (int*)alloc((size_t)N * sizeof(int));
  int* bsum = (int*)alloc(256 * sizeof(int));
  int* bpre = (int*)alloc(256 * sizeof(int));
  unsigned* rec = (unsigned*)alloc((size_t)E * sizeof(unsigned));  // 2.4 MB
  int* perm = (int*)alloc((size_t)E * sizeof(int));                // 2.4 MB
  float* csr_w = (float*)alloc((size_t)E * sizeof(float));         // 2.4 MB
  unsigned short* src16 =
      (unsigned short*)alloc((size_t)E * sizeof(unsigned short));
  float* h0 = (float*)alloc((size_t)N * sizeof(float));
  float* f_a = (float*)alloc((size_t)N * sizeof(float));
  float* f_b = (float*)alloc((size_t)N * sizeof(float));
  float* rsd = (float*)alloc((size_t)N * sizeof(float));
  (void)ws_size;

  const int NB_N = (N + 255) / 256;  // 196 <= 256 (scan_b capacity)
  const int nb_E = (E + 255) / 256;

  hipMemsetAsync(cnt, 0, (size_t)N * sizeof(int), stream);
  // histogram cols + node inits (h0, f_a)
  k_init_count<<<nb_E, 256, 0, stream>>>(cols, mask, cnt, h0, f_a, N, E);
  // MFMA GEMM + tanh + normalize + fp16 store
  k_gemm_mfma<<<(N + 63) / 64, 256, 0, stream>>>(x, W, bl, hn, N);
  // exclusive scan of cnt -> off, cursor
  k_scan_a<<<NB_N, 256, 0, stream>>>(cnt, bsum, N);
  k_scan_b<<<1, 256, 0, stream>>>(bsum, bpre, NB_N);
  k_scan_c<<<NB_N, 256, 0, stream>>>(cnt, bpre, off, cursor, N, E);
  // col-sorted edge records + inverse permutation
  k_build<<<nb_E, 256, 0, stream>>>(rows, cols, cursor, rec, perm, E);
  // cosine in sorted order -> csr_w + src16 (sequential writes only)
  k_edge_cos<<<(E * 4 + 255) / 256, 256, 0, stream>>>(hn, rec, csr_w, src16,
                                                      E);
  // un-permute raw weights to ew (d_out) + segmented degree -> rsd
  k_unperm_rsd<<<nb_E, 256, 0, stream>>>(csr_w, perm, off, ew, rsd, N, E);
  // K=5 APPNP iterations (gather-reduce; iter 0 normalizes csr_w in place)
  const float* fi = f_a;
  float* fo = f_b;
  for (int it = 0; it < 5; ++it) {
    int mode = (it == 0 ? 1 : 0) | (it == 4 ? 2 : 0);
    k_prop<<<(N * 4 + 255) / 256, 256, 0, stream>>>(
        fi, fo, csr_w, src16, off, h0, rsd, alpha, bias, fill, N, mode);
    const float* tmp = fo;
    fo = (float*)fi;
    fi = tmp;
  }
}